// Round 1
// baseline (3236.112 us; speedup 1.0000x reference)
//
#include <hip/hip_runtime.h>
#include <hip/hip_bf16.h>
#include <stdint.h>

#define B_   256
#define T_   512
#define DIN  128
#define DST  128
#define DHID 512

typedef __attribute__((ext_vector_type(8))) short bf16x8;
typedef __attribute__((ext_vector_type(4))) float f32x4;

static __device__ __forceinline__ unsigned short f2bf(float f) {
    union { float f; unsigned int u; } v; v.f = f;
    unsigned int u = v.u;
    unsigned int rounding = 0x7FFFu + ((u >> 16) & 1u);
    u += rounding;
    return (unsigned short)(u >> 16);
}

// ---- prep: W1 [256][512] -> W1T bf16 [512][256]  (out[n*256+k] = W1[k*512+n])
__global__ void cvt_w1t(const float* __restrict__ w1, unsigned short* __restrict__ out) {
    int tid = blockIdx.x * blockDim.x + threadIdx.x;   // 131072 total
    int n = tid >> 8;          // 0..511
    int k = tid & 255;         // 0..255
    out[tid] = f2bf(w1[k * DHID + n]);
}

// ---- prep: W2 [512][128] -> W2T bf16 [128][512]  (out[n*512+h] = W2[h*128+n])
__global__ void cvt_w2t(const float* __restrict__ w2, unsigned short* __restrict__ out) {
    int tid = blockIdx.x * blockDim.x + threadIdx.x;   // 65536 total
    int n = tid >> 9;          // 0..127
    int h = tid & 511;         // 0..511
    out[tid] = f2bf(w2[h * DST + n]);
}

// ---- main persistent RNN kernel: 16 blocks x 512 threads, block g owns rows [16g, 16g+16)
__global__ __launch_bounds__(512) void rnn_main(
    const float* __restrict__ x,      // [B][T][DIN] fp32
    const unsigned short* __restrict__ w1t,  // [512][256] bf16
    const unsigned short* __restrict__ w2t,  // [128][512] bf16
    const float* __restrict__ a0,     // [B][DST]
    const float* __restrict__ b1,     // [DHID]
    const float* __restrict__ b2,     // [DST]
    float* __restrict__ out)          // [B][DST]
{
    __shared__ unsigned short Hs[16 * DHID];   // bf16, row stride 1024B, XOR-swizzled
    __shared__ unsigned short a_bf[16 * DST];  // bf16, row stride 256B, XOR-swizzled
    __shared__ float a_f[16 * DST];            // fp32 master state, linear

    const int tid  = threadIdx.x;
    const int lane = tid & 63;
    const int w    = tid >> 6;     // wave 0..7
    const int bg   = blockIdx.x * 16;

    const int lr = lane & 15;      // tile row/col index
    const int lg = lane >> 4;      // k-group 0..3

    // init state a
    for (int i = tid; i < 16 * DST; i += 512) {
        int r = i >> 7, c = i & 127;
        float v = a0[(size_t)(bg + r) * DST + c];
        a_f[i] = v;
        int byte = r * 256 + ((c * 2) ^ ((r & 7) << 4));
        *(unsigned short*)((char*)a_bf + byte) = f2bf(v);
    }

    // biases (loop-invariant, keep in regs)
    float b1v[4];
#pragma unroll
    for (int j = 0; j < 4; ++j) b1v[j] = b1[w * 64 + j * 16 + lr];
    const float b2v = b2[w * 16 + lr];

    __syncthreads();

    for (int t = 0; t < T_; ++t) {
        // ================= GEMM1: H[16][512] = tanh(Xa @ W1 + b1) =================
        // wave w computes cols [64w, 64w+64): 4 N-tiles, K=256 (8 k-steps of 32)
        f32x4 acc0 = (f32x4)(0.0f), acc1 = (f32x4)(0.0f),
              acc2 = (f32x4)(0.0f), acc3 = (f32x4)(0.0f);

        bf16x8 afr[8];
        // x part (k = 0..127): fp32 load + convert in-register
        {
            const float* xr = x + (size_t)(bg + lr) * (T_ * DIN) + (size_t)t * DIN + lg * 8;
#pragma unroll
            for (int kk = 0; kk < 4; ++kk) {
                float4 p = *reinterpret_cast<const float4*>(xr + kk * 32);
                float4 q = *reinterpret_cast<const float4*>(xr + kk * 32 + 4);
                union { bf16x8 v; unsigned short u[8]; } cv;
                cv.u[0] = f2bf(p.x); cv.u[1] = f2bf(p.y);
                cv.u[2] = f2bf(p.z); cv.u[3] = f2bf(p.w);
                cv.u[4] = f2bf(q.x); cv.u[5] = f2bf(q.y);
                cv.u[6] = f2bf(q.z); cv.u[7] = f2bf(q.w);
                afr[kk] = cv.v;
            }
        }
        // a part (k = 128..255): from swizzled LDS bf16
#pragma unroll
        for (int kk = 0; kk < 4; ++kk) {
            int byte = lr * 256 + (((kk * 32 + lg * 8) * 2) ^ ((lr & 7) << 4));
            afr[4 + kk] = *reinterpret_cast<const bf16x8*>((char*)a_bf + byte);
        }

        // B-frags straight from global (L2-resident weights), 4 N-tiles
        {
            const unsigned short* wr0 = w1t + (size_t)(w * 64 +  0 + lr) * 256 + lg * 8;
            const unsigned short* wr1 = w1t + (size_t)(w * 64 + 16 + lr) * 256 + lg * 8;
            const unsigned short* wr2 = w1t + (size_t)(w * 64 + 32 + lr) * 256 + lg * 8;
            const unsigned short* wr3 = w1t + (size_t)(w * 64 + 48 + lr) * 256 + lg * 8;
#pragma unroll
            for (int kk = 0; kk < 8; ++kk) {
                bf16x8 bf0 = *reinterpret_cast<const bf16x8*>(wr0 + kk * 32);
                bf16x8 bf1 = *reinterpret_cast<const bf16x8*>(wr1 + kk * 32);
                bf16x8 bf2 = *reinterpret_cast<const bf16x8*>(wr2 + kk * 32);
                bf16x8 bf3 = *reinterpret_cast<const bf16x8*>(wr3 + kk * 32);
                acc0 = __builtin_amdgcn_mfma_f32_16x16x32_bf16(afr[kk], bf0, acc0, 0, 0, 0);
                acc1 = __builtin_amdgcn_mfma_f32_16x16x32_bf16(afr[kk], bf1, acc1, 0, 0, 0);
                acc2 = __builtin_amdgcn_mfma_f32_16x16x32_bf16(afr[kk], bf2, acc2, 0, 0, 0);
                acc3 = __builtin_amdgcn_mfma_f32_16x16x32_bf16(afr[kk], bf3, acc3, 0, 0, 0);
            }
        }

        // tanh + store H to LDS (C/D layout: row=lg*4+r, col=lr within tile)
        {
            f32x4 av[4] = {acc0, acc1, acc2, acc3};
#pragma unroll
            for (int j = 0; j < 4; ++j) {
#pragma unroll
                for (int r = 0; r < 4; ++r) {
                    float v = av[j][r] + b1v[j];
                    float e = __expf(2.0f * v);
                    float th = 1.0f - 2.0f / (e + 1.0f);
                    int row = lg * 4 + r;
                    int col = w * 64 + j * 16 + lr;
                    int byte = row * 1024 + ((col * 2) ^ ((row & 7) << 4));
                    *(unsigned short*)((char*)Hs + byte) = f2bf(th);
                }
            }
        }
        __syncthreads();

        // ================= GEMM2: S[16][128] = H @ W2 + b2 =================
        // wave w computes cols [16w,16w+16): 1 N-tile, K=512 split into 2 chains (ILP=2)
        f32x4 s0 = (f32x4)(0.0f), s1 = (f32x4)(0.0f);
        {
            const unsigned short* w2r = w2t + (size_t)(w * 16 + lr) * 512 + lg * 8;
#pragma unroll
            for (int kk = 0; kk < 8; ++kk) {
                int k0 = kk * 32;
                int k1 = 256 + kk * 32;
                int byte0 = lr * 1024 + (((k0 + lg * 8) * 2) ^ ((lr & 7) << 4));
                int byte1 = lr * 1024 + (((k1 + lg * 8) * 2) ^ ((lr & 7) << 4));
                bf16x8 ha0 = *reinterpret_cast<const bf16x8*>((char*)Hs + byte0);
                bf16x8 ha1 = *reinterpret_cast<const bf16x8*>((char*)Hs + byte1);
                bf16x8 bb0 = *reinterpret_cast<const bf16x8*>(w2r + k0);
                bf16x8 bb1 = *reinterpret_cast<const bf16x8*>(w2r + k1);
                s0 = __builtin_amdgcn_mfma_f32_16x16x32_bf16(ha0, bb0, s0, 0, 0, 0);
                s1 = __builtin_amdgcn_mfma_f32_16x16x32_bf16(ha1, bb1, s1, 0, 0, 0);
            }
        }

        // a += S + b2 (each (row,col) owned by exactly one lane)
#pragma unroll
        for (int r = 0; r < 4; ++r) {
            int row = lg * 4 + r;
            int col = w * 16 + lr;
            float v = a_f[row * 128 + col] + s0[r] + s1[r] + b2v;
            a_f[row * 128 + col] = v;
            int byte = row * 256 + ((col * 2) ^ ((row & 7) << 4));
            *(unsigned short*)((char*)a_bf + byte) = f2bf(v);
        }
        __syncthreads();
    }

    // epilogue: write final a
    for (int i = tid; i < 16 * DST; i += 512) {
        int r = i >> 7, c = i & 127;
        out[(size_t)(bg + r) * DST + c] = a_f[i];
    }
}

extern "C" void kernel_launch(void* const* d_in, const int* in_sizes, int n_in,
                              void* d_out, int out_size, void* d_ws, size_t ws_size,
                              hipStream_t stream) {
    const float* x  = (const float*)d_in[0];
    const float* a0 = (const float*)d_in[1];
    const float* W1 = (const float*)d_in[2];
    const float* b1 = (const float*)d_in[3];
    const float* W2 = (const float*)d_in[4];
    const float* b2 = (const float*)d_in[5];

    unsigned short* w1t = (unsigned short*)d_ws;            // 512*256 bf16 = 256 KB
    unsigned short* w2t = w1t + 512 * 256;                  // 128*512 bf16 = 128 KB

    cvt_w1t<<<512, 256, 0, stream>>>(W1, w1t);
    cvt_w2t<<<256, 256, 0, stream>>>(W2, w2t);
    rnn_main<<<16, 512, 0, stream>>>(x, w1t, w2t, a0, b1, b2, (float*)d_out);
}

// Round 2
// 1904.657 us; speedup vs baseline: 1.6991x; 1.6991x over previous
//
#include <hip/hip_runtime.h>
#include <hip/hip_bf16.h>
#include <stdint.h>

#define B_   256
#define T_   512
#define DIN  128
#define DST  128
#define DHID 512

typedef __attribute__((ext_vector_type(8))) short bf16x8;
typedef __attribute__((ext_vector_type(4))) float f32x4;

static __device__ __forceinline__ unsigned short f2bf(float f) {
    union { float f; unsigned int u; } v; v.f = f;
    unsigned int u = v.u;
    unsigned int rounding = 0x7FFFu + ((u >> 16) & 1u);
    u += rounding;
    return (unsigned short)(u >> 16);
}

static __device__ __forceinline__ void gload_lds16(const void* g, void* l) {
    __builtin_amdgcn_global_load_lds(
        (const __attribute__((address_space(1))) unsigned int*)g,
        (__attribute__((address_space(3))) unsigned int*)l,
        16, 0, 0);
}

// ---- prep: W1 [256][512] -> W1T bf16 [512][256]
__global__ void cvt_w1t(const float* __restrict__ w1, unsigned short* __restrict__ out) {
    int tid = blockIdx.x * blockDim.x + threadIdx.x;   // 131072
    int n = tid >> 8;
    int k = tid & 255;
    out[tid] = f2bf(w1[k * DHID + n]);
}

// ---- prep: W2 [512][128] -> W2T bf16 [128][512]
__global__ void cvt_w2t(const float* __restrict__ w2, unsigned short* __restrict__ out) {
    int tid = blockIdx.x * blockDim.x + threadIdx.x;   // 65536
    int n = tid >> 9;
    int h = tid & 511;
    out[tid] = f2bf(w2[h * DST + n]);
}

// ---- prep: x fp32 [256][512][128] -> bf16, per-(block,t) 4KB tiles, XOR-swizzled
// chunk(g,t) byte base = (g*512+t)*4096 ; within: r*256 + ((2k) ^ ((r&7)<<4))
__global__ void cvt_x(const float* __restrict__ x, unsigned short* __restrict__ wsx) {
    int tid = blockIdx.x * blockDim.x + threadIdx.x;   // 2,097,152
    int q  = tid & 15;            // 16B chunk within row (k0 = q*8)
    int t  = (tid >> 4) & 511;
    int br = tid >> 13;           // 0..255
    int g  = br >> 4, r = br & 15;
    const float* src = x + ((size_t)br * T_ + t) * DIN + q * 8;
    float4 p = *reinterpret_cast<const float4*>(src);
    float4 s = *reinterpret_cast<const float4*>(src + 4);
    union { bf16x8 v; unsigned short u[8]; } cv;
    cv.u[0] = f2bf(p.x); cv.u[1] = f2bf(p.y); cv.u[2] = f2bf(p.z); cv.u[3] = f2bf(p.w);
    cv.u[4] = f2bf(s.x); cv.u[5] = f2bf(s.y); cv.u[6] = f2bf(s.z); cv.u[7] = f2bf(s.w);
    size_t base = ((size_t)(g * T_ + t)) * 4096 + (size_t)r * 256 + (size_t)((q * 16) ^ ((r & 7) << 4));
    *reinterpret_cast<bf16x8*>((char*)wsx + base) = cv.v;
}

// ---- main: 16 blocks x 512 threads (8 waves), block g owns batch rows [16g,16g+16)
template<bool XLDS>
__global__ __launch_bounds__(512, 2) void rnn_main(
    const float* __restrict__ x,             // fallback path
    const unsigned short* __restrict__ wsx,  // swizzled bf16 x tiles
    const unsigned short* __restrict__ w1t,  // [512][256] bf16
    const unsigned short* __restrict__ w2t,  // [128][512] bf16
    const float* __restrict__ a0,
    const float* __restrict__ b1,
    const float* __restrict__ b2,
    float* __restrict__ out)
{
    __shared__ unsigned short Hs[16 * DHID];      // 16 KB, row stride 1024B, swizzled
    __shared__ unsigned short a_bf[16 * DST];     // 4 KB, row stride 256B, swizzled
    __shared__ unsigned short xbuf[2][16 * DIN];  // 2 x 4 KB, swizzled

    const int tid  = threadIdx.x;
    const int lane = tid & 63;
    const int w    = tid >> 6;
    const int bg   = blockIdx.x * 16;
    const int lr   = lane & 15;
    const int lg   = lane >> 4;
    const int swz  = (lr & 7) << 4;

    // ---- hoist ALL weights into registers (loop-invariant) ----
    bf16x8 W1f[4][8];   // 128 VGPR
#pragma unroll
    for (int j = 0; j < 4; ++j) {
        const unsigned short* wr = w1t + (size_t)(w * 64 + j * 16 + lr) * 256 + lg * 8;
#pragma unroll
        for (int kk = 0; kk < 8; ++kk)
            W1f[j][kk] = *reinterpret_cast<const bf16x8*>(wr + kk * 32);
    }
    bf16x8 W2f[8][2];   // 64 VGPR
    {
        const unsigned short* wr = w2t + (size_t)(w * 16 + lr) * 512 + lg * 8;
#pragma unroll
        for (int kk = 0; kk < 8; ++kk) {
            W2f[kk][0] = *reinterpret_cast<const bf16x8*>(wr + kk * 32);
            W2f[kk][1] = *reinterpret_cast<const bf16x8*>(wr + 256 + kk * 32);
        }
    }

    // ---- state in registers: lane owns a[row=lg*4+r][col=w*16+lr] ----
    float a_reg[4];
#pragma unroll
    for (int r = 0; r < 4; ++r)
        a_reg[r] = a0[(size_t)(bg + lg * 4 + r) * DST + w * 16 + lr];
#pragma unroll
    for (int r = 0; r < 4; ++r) {
        int row = lg * 4 + r, col = w * 16 + lr;
        *(unsigned short*)((char*)a_bf + row * 256 + ((col * 2) ^ ((row & 7) << 4))) = f2bf(a_reg[r]);
    }

    float b1v[4];
#pragma unroll
    for (int j = 0; j < 4; ++j) b1v[j] = b1[w * 64 + j * 16 + lr];
    const float b2v = b2[w * 16 + lr];

    // ---- prologue: stage x(0) into xbuf[0] ----
    if constexpr (XLDS) {
        if (tid < 256) {
            const char* src = (const char*)wsx + (size_t)blockIdx.x * T_ * 4096 + (size_t)tid * 16;
            gload_lds16(src, (char*)&xbuf[0][0] + w * 1024);
        }
    }
    __syncthreads();   // drains vmcnt; a_bf + xbuf[0] visible

    for (int t = 0; t < T_; ++t) {
        const char* xb = (const char*)&xbuf[t & 1][0];

        // prefetch x(t+1) into the other buffer (waves 0-3, 1 load/lane, 0 VGPR cost)
        if constexpr (XLDS) {
            if (tid < 256) {
                int tn = (t + 1 < T_) ? t + 1 : T_ - 1;
                const char* src = (const char*)wsx + ((size_t)(blockIdx.x * T_ + tn)) * 4096 + (size_t)tid * 16;
                gload_lds16(src, (char*)&xbuf[(t + 1) & 1][0] + w * 1024);
            }
        }

        bf16x8 xfr[4];
        if constexpr (!XLDS) {
            const float* xr = x + (size_t)(bg + lr) * (T_ * DIN) + (size_t)t * DIN + lg * 8;
#pragma unroll
            for (int kk = 0; kk < 4; ++kk) {
                float4 p = *reinterpret_cast<const float4*>(xr + kk * 32);
                float4 q = *reinterpret_cast<const float4*>(xr + kk * 32 + 4);
                union { bf16x8 v; unsigned short u[8]; } cv;
                cv.u[0] = f2bf(p.x); cv.u[1] = f2bf(p.y); cv.u[2] = f2bf(p.z); cv.u[3] = f2bf(p.w);
                cv.u[4] = f2bf(q.x); cv.u[5] = f2bf(q.y); cv.u[6] = f2bf(q.z); cv.u[7] = f2bf(q.w);
                xfr[kk] = cv.v;
            }
        }

        // ============ GEMM1: H[16][512] = tanh([x;a] @ W1 + b1), wave w -> cols 64w..64w+64 ============
        f32x4 acc[4];
#pragma unroll
        for (int j = 0; j < 4; ++j) acc[j] = (f32x4)(0.0f);

#pragma unroll
        for (int kk = 0; kk < 8; ++kk) {
            bf16x8 af;
            if (kk < 4) {
                if constexpr (XLDS)
                    af = *reinterpret_cast<const bf16x8*>(xb + lr * 256 + ((kk * 64 + lg * 16) ^ swz));
                else
                    af = xfr[kk & 3];
            } else {
                af = *reinterpret_cast<const bf16x8*>((const char*)a_bf + lr * 256 + (((kk - 4) * 64 + lg * 16) ^ swz));
            }
#pragma unroll
            for (int j = 0; j < 4; ++j)
                acc[j] = __builtin_amdgcn_mfma_f32_16x16x32_bf16(af, W1f[j][kk], acc[j], 0, 0, 0);
        }

        // tanh + store H (C/D layout: row=lg*4+r, col=w*64+j*16+lr)
#pragma unroll
        for (int j = 0; j < 4; ++j) {
#pragma unroll
            for (int r = 0; r < 4; ++r) {
                float v = acc[j][r] + b1v[j];
                float e = __expf(2.0f * v);
                float th = 1.0f - 2.0f / (e + 1.0f);
                int row = lg * 4 + r;
                int col = w * 64 + j * 16 + lr;
                *(unsigned short*)((char*)Hs + row * 1024 + ((col * 2) ^ ((row & 7) << 4))) = f2bf(th);
            }
        }
        __syncthreads();

        // ============ GEMM2: S[16][128] = H @ W2 + b2, wave w -> cols 16w..16w+16 ============
        f32x4 s0 = (f32x4)(0.0f), s1 = (f32x4)(0.0f);
#pragma unroll
        for (int kk = 0; kk < 8; ++kk) {
            bf16x8 h0 = *reinterpret_cast<const bf16x8*>((const char*)Hs + lr * 1024 + ((kk * 64 + lg * 16) ^ swz));
            bf16x8 h1 = *reinterpret_cast<const bf16x8*>((const char*)Hs + lr * 1024 + ((512 + kk * 64 + lg * 16) ^ swz));
            s0 = __builtin_amdgcn_mfma_f32_16x16x32_bf16(h0, W2f[kk][0], s0, 0, 0, 0);
            s1 = __builtin_amdgcn_mfma_f32_16x16x32_bf16(h1, W2f[kk][1], s1, 0, 0, 0);
        }

        // a += S + b2 ; publish bf16 state
#pragma unroll
        for (int r = 0; r < 4; ++r) {
            float v = a_reg[r] + s0[r] + s1[r] + b2v;
            a_reg[r] = v;
            int row = lg * 4 + r, col = w * 16 + lr;
            *(unsigned short*)((char*)a_bf + row * 256 + ((col * 2) ^ ((row & 7) << 4))) = f2bf(v);
        }
        __syncthreads();   // also drains the x-prefetch vmcnt on waves 0-3
    }

    // epilogue
#pragma unroll
    for (int r = 0; r < 4; ++r)
        out[(size_t)(bg + lg * 4 + r) * DST + w * 16 + lr] = a_reg[r];
}

extern "C" void kernel_launch(void* const* d_in, const int* in_sizes, int n_in,
                              void* d_out, int out_size, void* d_ws, size_t ws_size,
                              hipStream_t stream) {
    const float* x  = (const float*)d_in[0];
    const float* a0 = (const float*)d_in[1];
    const float* W1 = (const float*)d_in[2];
    const float* b1 = (const float*)d_in[3];
    const float* W2 = (const float*)d_in[4];
    const float* b2 = (const float*)d_in[5];

    unsigned short* w1t = (unsigned short*)d_ws;            // 256 KB
    unsigned short* w2t = w1t + 512 * 256;                  // 128 KB
    unsigned short* wsx = w2t + 128 * 512;                  // 32 MB (offset 384 KB)
    const size_t need = (size_t)384 * 1024 + (size_t)B_ * T_ * DIN * 2;

    cvt_w1t<<<512, 256, 0, stream>>>(W1, w1t);
    cvt_w2t<<<256, 256, 0, stream>>>(W2, w2t);

    if (ws_size >= need) {
        cvt_x<<<8192, 256, 0, stream>>>(x, wsx);
        rnn_main<true><<<16, 512, 0, stream>>>(x, wsx, w1t, w2t, a0, b1, b2, (float*)d_out);
    } else {
        rnn_main<false><<<16, 512, 0, stream>>>(x, wsx, w1t, w2t, a0, b1, b2, (float*)d_out);
    }
}